// Round 15
// baseline (985.955 us; speedup 1.0000x reference)
//
#include <hip/hip_runtime.h>
#include <stdint.h>
#include <math.h>

#define VV 128000
#define DD 2048
#define BB 32
#define SS 8
#define NCAND 4096
#define KSPLIT 4
#define KSL 512            // k per split
#define WS_NEED ((size_t)KSPLIT * BB * VV * 4)

// jax_threefry_partitionable 32-bit stream: counter=(0,flat), bits = o0 ^ o1.  (verified R4+)

#define GLDS(src, dst) __builtin_amdgcn_global_load_lds( \
    (const __attribute__((address_space(1))) void*)(src), \
    (__attribute__((address_space(3))) void*)(dst), 16, 0, 0)
#define CBAR() asm volatile("" ::: "memory")

// ---------------- threefry2x32 core (key = (0, 42) from jax.random.key(42)) ----------------
__device__ __forceinline__ uint32_t rotl32(uint32_t x, uint32_t r) {
    return (x << r) | (x >> (32u - r));
}

__device__ __forceinline__ void threefry2x32(uint32_t c0, uint32_t c1,
                                             uint32_t& o0, uint32_t& o1) {
    const uint32_t k0 = 0u, k1 = 42u;
    const uint32_t k2 = 0x1BD11BDAu ^ k0 ^ k1;
    uint32_t x0 = c0 + k0;
    uint32_t x1 = c1 + k1;
    #define TF_ROUND(r) { x0 += x1; x1 = rotl32(x1, r); x1 ^= x0; }
    TF_ROUND(13) TF_ROUND(15) TF_ROUND(26) TF_ROUND(6)
    x0 += k1; x1 += k2 + 1u;
    TF_ROUND(17) TF_ROUND(29) TF_ROUND(16) TF_ROUND(24)
    x0 += k2; x1 += k0 + 2u;
    TF_ROUND(13) TF_ROUND(15) TF_ROUND(26) TF_ROUND(6)
    x0 += k0; x1 += k1 + 3u;
    TF_ROUND(17) TF_ROUND(29) TF_ROUND(16) TF_ROUND(24)
    x0 += k1; x1 += k2 + 4u;
    TF_ROUND(13) TF_ROUND(15) TF_ROUND(26) TF_ROUND(6)
    x0 += k2; x1 += k0 + 5u;
    #undef TF_ROUND
    o0 = x0; o1 = x1;
}

__device__ float gumbel_at(uint32_t flat) {
    uint32_t o0, o1;
    threefry2x32(0u, flat, o0, o1);
    uint32_t bits = o0 ^ o1;
    uint32_t fb = (bits >> 9) | 0x3F800000u;
    float f = __uint_as_float(fb) - 1.0f;
    const float TINY = 1.17549435e-38f;
    float u = (f > 0.0f) ? f : TINY;
    return -logf(-logf(u));
}

__device__ __forceinline__ uint32_t enc_f32(float f) {
    uint32_t u = __float_as_uint(f);
    return u ^ (0x80000000u | (uint32_t)(((int32_t)u) >> 31));
}

// ---------------- K1a: partial GEMV over one K-slice ----------------
// grid (VV/32, KSPLIT) x 512 thr (8 waves). Block: 32 v x 32 b x 512 k.
// Wave w: batch-half (w&1)*16, v-oct (w>>1)*8. Lane: kl=lane&15 (k slot),
// bl=lane>>4 (batch quad). Thread tile 8v x 4b (acc 32) -> 2 FMA per LDS
// byte (LDS total 4.2 GB). h[32][512] (64 KB) staged once via GLDS + ONE
// vmcnt(8)+barrier (8 e-loads ride through); then 8 chunks of straight-line
// code with depth-1 group-ping-pong e prefetch, ZERO in-loop barriers or
// manual waitcnts (compiler dependency waits only).
// k-order per acc (kl*4+c*64, c asc, xyzw), shuffle tree, ws layout and
// reduce_ep identical to R14 -> bit-identical logits/tokens.
__global__ __launch_bounds__(512, 4) void gemv_part(
    const float* __restrict__ emb, const float* __restrict__ hidden,
    const int* __restrict__ outpos, float* __restrict__ ws)
{
    __shared__ float h[BB][KSL];   // 64 KB

    const int tid   = threadIdx.x;
    const int w     = tid >> 6;
    const int lane  = tid & 63;
    const int kl    = lane & 15;
    const int bl    = lane >> 4;
    const int ky    = blockIdx.y;
    const int vbase = blockIdx.x * 32;
    const int pos   = outpos[0];
    const int bhalf = (w & 1) * 16;
    const int voct  = (w >> 1) * 8;

    const float* hbase = hidden + (size_t)pos * DD + ky * KSL;

    // stage h[32][512]: instr (i,w): x=i*8+w -> row x>>1, half x&1  (R14-proven)
    #pragma unroll
    for (int i = 0; i < 8; ++i) {
        const int x = i * 8 + w;
        GLDS(hbase + (size_t)(x >> 1) * (SS * DD) + (x & 1) * 256 + (lane << 2),
             &h[x >> 1][(x & 1) * 256]);
    }
    CBAR();

    // e row pointers: this wave's 8 v-rows at this lane's kl slot
    const float* er0 = emb + (size_t)(vbase + voct + 0) * DD + ky * KSL + (kl << 2);
    const float* er1 = er0 + DD;
    const float* er2 = er1 + DD;
    const float* er3 = er2 + DD;
    const float* er4 = er3 + DD;
    const float* er5 = er4 + DD;
    const float* er6 = er5 + DD;
    const float* er7 = er6 + DD;

    // prologue: e chunk 0 (two groups) issued while staging flies
    float4 a0 = *reinterpret_cast<const float4*>(er0);
    float4 a1 = *reinterpret_cast<const float4*>(er1);
    float4 a2 = *reinterpret_cast<const float4*>(er2);
    float4 a3 = *reinterpret_cast<const float4*>(er3);
    float4 b0 = *reinterpret_cast<const float4*>(er4);
    float4 b1 = *reinterpret_cast<const float4*>(er5);
    float4 b2 = *reinterpret_cast<const float4*>(er6);
    float4 b3 = *reinterpret_cast<const float4*>(er7);
    float4 na0, na1, na2, na3, nb0, nb1, nb2, nb3;
    CBAR();
    asm volatile("s_waitcnt vmcnt(8)" ::: "memory");   // 8 GLDS retired; e flying
    __builtin_amdgcn_s_barrier();
    CBAR();

    float acc[8][4];
    #pragma unroll
    for (int v = 0; v < 8; ++v)
        #pragma unroll
        for (int j = 0; j < 4; ++j) acc[v][j] = 0.0f;

    // ds base: this thread's 4 batch rows start; j*2048 + c*256 are immediates
    const char* dsb = (const char*)&h[0][0] + (size_t)(bhalf + bl * 4) * 2048 + (kl << 4);

    #define FMAG(VB, E0, E1, E2, E3) \
        acc[VB+0][0] += E0.x * h0.x; acc[VB+0][0] += E0.y * h0.y; \
        acc[VB+0][0] += E0.z * h0.z; acc[VB+0][0] += E0.w * h0.w; \
        acc[VB+0][1] += E0.x * h1.x; acc[VB+0][1] += E0.y * h1.y; \
        acc[VB+0][1] += E0.z * h1.z; acc[VB+0][1] += E0.w * h1.w; \
        acc[VB+0][2] += E0.x * h2.x; acc[VB+0][2] += E0.y * h2.y; \
        acc[VB+0][2] += E0.z * h2.z; acc[VB+0][2] += E0.w * h2.w; \
        acc[VB+0][3] += E0.x * h3.x; acc[VB+0][3] += E0.y * h3.y; \
        acc[VB+0][3] += E0.z * h3.z; acc[VB+0][3] += E0.w * h3.w; \
        acc[VB+1][0] += E1.x * h0.x; acc[VB+1][0] += E1.y * h0.y; \
        acc[VB+1][0] += E1.z * h0.z; acc[VB+1][0] += E1.w * h0.w; \
        acc[VB+1][1] += E1.x * h1.x; acc[VB+1][1] += E1.y * h1.y; \
        acc[VB+1][1] += E1.z * h1.z; acc[VB+1][1] += E1.w * h1.w; \
        acc[VB+1][2] += E1.x * h2.x; acc[VB+1][2] += E1.y * h2.y; \
        acc[VB+1][2] += E1.z * h2.z; acc[VB+1][2] += E1.w * h2.w; \
        acc[VB+1][3] += E1.x * h3.x; acc[VB+1][3] += E1.y * h3.y; \
        acc[VB+1][3] += E1.z * h3.z; acc[VB+1][3] += E1.w * h3.w; \
        acc[VB+2][0] += E2.x * h0.x; acc[VB+2][0] += E2.y * h0.y; \
        acc[VB+2][0] += E2.z * h0.z; acc[VB+2][0] += E2.w * h0.w; \
        acc[VB+2][1] += E2.x * h1.x; acc[VB+2][1] += E2.y * h1.y; \
        acc[VB+2][1] += E2.z * h1.z; acc[VB+2][1] += E2.w * h1.w; \
        acc[VB+2][2] += E2.x * h2.x; acc[VB+2][2] += E2.y * h2.y; \
        acc[VB+2][2] += E2.z * h2.z; acc[VB+2][2] += E2.w * h2.w; \
        acc[VB+2][3] += E2.x * h3.x; acc[VB+2][3] += E2.y * h3.y; \
        acc[VB+2][3] += E2.z * h3.z; acc[VB+2][3] += E2.w * h3.w; \
        acc[VB+3][0] += E3.x * h0.x; acc[VB+3][0] += E3.y * h0.y; \
        acc[VB+3][0] += E3.z * h0.z; acc[VB+3][0] += E3.w * h0.w; \
        acc[VB+3][1] += E3.x * h1.x; acc[VB+3][1] += E3.y * h1.y; \
        acc[VB+3][1] += E3.z * h1.z; acc[VB+3][1] += E3.w * h1.w; \
        acc[VB+3][2] += E3.x * h2.x; acc[VB+3][2] += E3.y * h2.y; \
        acc[VB+3][2] += E3.z * h2.z; acc[VB+3][2] += E3.w * h2.w; \
        acc[VB+3][3] += E3.x * h3.x; acc[VB+3][3] += E3.y * h3.y; \
        acc[VB+3][3] += E3.z * h3.z; acc[VB+3][3] += E3.w * h3.w;

    // one chunk: ds x4 -> FMA G0 -> prefetch G0(c+1) -> FMA G1 -> prefetch G1(c+1)
    #define CHUNK(C, A0,A1,A2,A3, B0,B1,B2,B3, NA0,NA1,NA2,NA3, NB0,NB1,NB2,NB3) { \
        const float4 h0 = *reinterpret_cast<const float4*>(dsb + 0 * 2048 + (C) * 256); \
        const float4 h1 = *reinterpret_cast<const float4*>(dsb + 1 * 2048 + (C) * 256); \
        const float4 h2 = *reinterpret_cast<const float4*>(dsb + 2 * 2048 + (C) * 256); \
        const float4 h3 = *reinterpret_cast<const float4*>(dsb + 3 * 2048 + (C) * 256); \
        CBAR(); \
        FMAG(0, A0, A1, A2, A3) \
        CBAR(); \
        { const int nc = ((C) + 1) & 7; \
          NA0 = *reinterpret_cast<const float4*>(er0 + nc * 64); \
          NA1 = *reinterpret_cast<const float4*>(er1 + nc * 64); \
          NA2 = *reinterpret_cast<const float4*>(er2 + nc * 64); \
          NA3 = *reinterpret_cast<const float4*>(er3 + nc * 64); } \
        CBAR(); \
        FMAG(4, B0, B1, B2, B3) \
        CBAR(); \
        { const int nc = ((C) + 1) & 7; \
          NB0 = *reinterpret_cast<const float4*>(er4 + nc * 64); \
          NB1 = *reinterpret_cast<const float4*>(er5 + nc * 64); \
          NB2 = *reinterpret_cast<const float4*>(er6 + nc * 64); \
          NB3 = *reinterpret_cast<const float4*>(er7 + nc * 64); } \
        CBAR(); \
    }

    #pragma unroll 1
    for (int d = 0; d < 4; ++d) {
        const int c0 = d * 2;
        CHUNK(c0,     a0,a1,a2,a3, b0,b1,b2,b3, na0,na1,na2,na3, nb0,nb1,nb2,nb3)
        CHUNK(c0 + 1, na0,na1,na2,na3, nb0,nb1,nb2,nb3, a0,a1,a2,a3, b0,b1,b2,b3)
    }
    #undef CHUNK
    #undef FMAG

    // keep final (wrapped) prefetch alive — deterministic codegen
    asm volatile("" :: "v"(a0.x), "v"(a1.x), "v"(a2.x), "v"(a3.x),
                       "v"(b0.x), "v"(b1.x), "v"(b2.x), "v"(b3.x));

    // reduce over the 16 kl lanes (identical tree to R13/R14)
    #pragma unroll
    for (int v = 0; v < 8; ++v)
        #pragma unroll
        for (int j = 0; j < 4; ++j) {
            float a = acc[v][j];
            a += __shfl_xor(a, 1, 64);
            a += __shfl_xor(a, 2, 64);
            a += __shfl_xor(a, 4, 64);
            a += __shfl_xor(a, 8, 64);
            acc[v][j] = a;
        }
    if (kl == 0) {
        #pragma unroll
        for (int v = 0; v < 8; ++v)
            #pragma unroll
            for (int j = 0; j < 4; ++j) {
                const int b = bhalf + bl * 4 + j;
                ws[((size_t)ky * BB + b) * VV + (vbase + voct + v)] = acc[v][j];
            }
    }
}

// ---------------- K1b: reduce K-splits + softcap/temperature epilogue ----------------
__global__ __launch_bounds__(512) void reduce_ep(
    const float* __restrict__ ws, const float* __restrict__ temps,
    float* __restrict__ out)
{
    const size_t flat = (size_t)blockIdx.x * 512 + threadIdx.x;   // < 32*VV
    const int b = (int)(flat / VV);
    const int v = (int)(flat - (size_t)b * VV);
    float s = 0.0f;
    #pragma unroll
    for (int ky = 0; ky < KSPLIT; ++ky)
        s += ws[((size_t)ky * BB + b) * VV + v];
    float l = tanhf(s / 30.0f) * 30.0f;    // final logit softcapping
    l = l / temps[b];                       // temperature
    out[32 + (size_t)b * VV + v] = l;
}

// ---------------- Fallback K1 (R12, passed) if ws too small ----------------
__global__ __launch_bounds__(512, 2) void gemv_fb(
    const float* __restrict__ emb, const float* __restrict__ hidden,
    const int* __restrict__ outpos, const float* __restrict__ temps,
    float* __restrict__ out)
{
    __shared__ float h[32][512];
    __shared__ float lout[32][33];

    const int tid   = threadIdx.x;
    const int w     = tid >> 6;
    const int lane  = tid & 63;
    const int kl    = lane & 15;
    const int bl    = lane >> 4;
    const int vbase = blockIdx.x * 32;
    const int pos   = outpos[0];

    const float* hbase = hidden + (size_t)pos * DD;
    const float* er0 = emb + (size_t)(vbase + w * 4 + 0) * DD + (kl << 2);
    const float* er1 = er0 + DD;
    const float* er2 = er1 + DD;
    const float* er3 = er2 + DD;

    int ads[8];
    #pragma unroll
    for (int j = 0; j < 8; ++j) ads[j] = ((bl * 8 + j) * 512 + (kl << 2)) * 4;
    char* hb = (char*)h;

    float acc[4][8];
    #pragma unroll
    for (int v = 0; v < 4; ++v)
        #pragma unroll
        for (int j = 0; j < 8; ++j) acc[v][j] = 0.0f;

    float4 eA0, eA1, eA2, eA3, eB0, eB1, eB2, eB3;

    #define STAGE(P) { \
        _Pragma("unroll") \
        for (int i = 0; i < 8; ++i) { \
            const int x = i * 8 + w; \
            const float* src = hbase + (size_t)(x >> 1) * (SS * DD) \
                             + (P) * 512 + (x & 1) * 256 + (lane << 2); \
            GLDS(src, &h[x >> 1][(x & 1) * 256]); \
        } }
    #define FMAQ(V, E, J) \
        acc[V][J] += E.x * hv.x; acc[V][J] += E.y * hv.y; \
        acc[V][J] += E.z * hv.z; acc[V][J] += E.w * hv.w;
    #define CHUNK(C, C0, C1, C2, C3, N0, N1, N2, N3) { \
        const int np = ((C) < 7) ? p : ((p < 3) ? p + 1 : 3); \
        const int nc = ((C) < 7) ? (C) + 1 : 0; \
        const int no = np * 512 + nc * 64; \
        N0 = *reinterpret_cast<const float4*>(er0 + no); \
        N1 = *reinterpret_cast<const float4*>(er1 + no); \
        N2 = *reinterpret_cast<const float4*>(er2 + no); \
        N3 = *reinterpret_cast<const float4*>(er3 + no); \
        _Pragma("unroll") \
        for (int j = 0; j < 8; ++j) { \
            const float4 hv = *reinterpret_cast<const float4*>(hb + ads[j] + (C) * 256); \
            FMAQ(0, C0, j) FMAQ(1, C1, j) FMAQ(2, C2, j) FMAQ(3, C3, j) \
        } }

    #pragma unroll 1
    for (int p = 0; p < 4; ++p) {
        if (p == 0) {
            STAGE(0)
            CBAR();
            eA0 = *reinterpret_cast<const float4*>(er0);
            eA1 = *reinterpret_cast<const float4*>(er1);
            eA2 = *reinterpret_cast<const float4*>(er2);
            eA3 = *reinterpret_cast<const float4*>(er3);
            CBAR();
            asm volatile("s_waitcnt vmcnt(4)" ::: "memory");
            __builtin_amdgcn_s_barrier();
        } else {
            __builtin_amdgcn_s_barrier();
            CBAR();
            STAGE(p)
            CBAR();
            asm volatile("s_waitcnt vmcnt(0)" ::: "memory");
            __builtin_amdgcn_s_barrier();
        }
        CBAR();
        CHUNK(0, eA0, eA1, eA2, eA3, eB0, eB1, eB2, eB3)
        CHUNK(1, eB0, eB1, eB2, eB3, eA0, eA1, eA2, eA3)
        CHUNK(2, eA0, eA1, eA2, eA3, eB0, eB1, eB2, eB3)
        CHUNK(3, eB0, eB1, eB2, eB3, eA0, eA1, eA2, eA3)
        CHUNK(4, eA0, eA1, eA2, eA3, eB0, eB1, eB2, eB3)
        CHUNK(5, eB0, eB1, eB2, eB3, eA0, eA1, eA2, eA3)
        CHUNK(6, eA0, eA1, eA2, eA3, eB0, eB1, eB2, eB3)
        CHUNK(7, eB0, eB1, eB2, eB3, eA0, eA1, eA2, eA3)
        CBAR();
    }
    #undef CHUNK
    #undef FMAQ
    #undef STAGE

    asm volatile("" :: "v"(eA0.x), "v"(eA1.x), "v"(eA2.x), "v"(eA3.x));

    #pragma unroll
    for (int v = 0; v < 4; ++v)
        #pragma unroll
        for (int j = 0; j < 8; ++j) {
            float a = acc[v][j];
            a += __shfl_xor(a, 1, 64);
            a += __shfl_xor(a, 2, 64);
            a += __shfl_xor(a, 4, 64);
            a += __shfl_xor(a, 8, 64);
            acc[v][j] = a;
        }

    __syncthreads();
    if (kl == 0) {
        #pragma unroll
        for (int v = 0; v < 4; ++v)
            #pragma unroll
            for (int j = 0; j < 8; ++j) {
                float raw = acc[v][j];
                float l = tanhf(raw / 30.0f) * 30.0f;
                l = l / temps[bl * 8 + j];
                lout[w * 4 + v][bl * 8 + j] = l;
            }
    }
    __syncthreads();
    #pragma unroll
    for (int r = 0; r < 2; ++r) {
        const int idx = tid + r * 512;
        const int b2  = idx >> 5;
        const int v2  = idx & 31;
        out[32 + (size_t)b2 * VV + vbase + v2] = lout[v2][b2];
    }
}

// ---------------- K2: per-row top-64 (prob-sorted, stable) + exact-RNG categorical ----------------
__global__ __launch_bounds__(1024) void sample_kernel(
    float* __restrict__ dout, const float* __restrict__ top_ps,
    const int* __restrict__ top_ks)
{
    const int b   = blockIdx.x;
    const int tid = threadIdx.x;
    const float* row = dout + 32 + (size_t)b * VV;

    __shared__ unsigned int hist[2048];
    __shared__ unsigned long long arr[NCAND];
    __shared__ float red[1024];
    __shared__ float m_sh;
    __shared__ unsigned int thresh_sh;
    __shared__ unsigned int cnt_sh;
    __shared__ float p_arr[64];
    __shared__ unsigned int idx_arr[64];
    __shared__ float S_sh;
    __shared__ unsigned long long keep_sh;

    for (int i = tid; i < 2048; i += 1024) hist[i] = 0u;
    for (int i = tid; i < NCAND; i += 1024) arr[i] = 0ull;
    if (tid == 0) cnt_sh = 0u;
    __syncthreads();

    float lmax = -INFINITY;
    for (int i = tid; i < VV; i += 1024) {
        float l = row[i];
        lmax = fmaxf(lmax, l);
        atomicAdd(&hist[enc_f32(l) >> 21], 1u);
    }
    red[tid] = lmax;
    __syncthreads();
    for (int s = 512; s > 0; s >>= 1) {
        if (tid < s) red[tid] = fmaxf(red[tid], red[tid + s]);
        __syncthreads();
    }
    if (tid == 0) {
        float m = red[0];
        m_sh = m;
        int t = (int)(enc_f32(m) >> 21);
        unsigned int cum = 0u;
        for (; t >= 0; --t) { cum += hist[t]; if (cum >= 64u) break; }
        if (t < 0) t = 0;
        thresh_sh = ((unsigned int)t) << 21;
    }
    __syncthreads();
    const float m = m_sh;
    const unsigned int thresh = thresh_sh;

    float z = 0.0f;
    for (int i = tid; i < VV; i += 1024) z += expf(row[i] - m);
    red[tid] = z;
    __syncthreads();
    for (int s = 512; s > 0; s >>= 1) {
        if (tid < s) red[tid] += red[tid + s];
        __syncthreads();
    }
    const float Z = red[0];
    __syncthreads();

    for (int i = tid; i < VV; i += 1024) {
        float l = row[i];
        if (enc_f32(l) >= thresh) {
            float p = expf(l - m) / Z;
            unsigned int slot = atomicAdd(&cnt_sh, 1u);
            if (slot < NCAND)
                arr[slot] = ((unsigned long long)enc_f32(p) << 32)
                          | (unsigned long long)(~(unsigned int)i);
        }
    }
    __syncthreads();

    for (int k = 2; k <= NCAND; k <<= 1) {
        for (int j = k >> 1; j > 0; j >>= 1) {
            for (int t = tid; t < NCAND; t += 1024) {
                int ixj = t ^ j;
                if (ixj > t) {
                    unsigned long long a = arr[t], c = arr[ixj];
                    bool desc = ((t & k) == 0);
                    if (desc ? (a < c) : (a > c)) { arr[t] = c; arr[ixj] = a; }
                }
            }
            __syncthreads();
        }
    }

    if (tid < 64) {
        unsigned long long key = arr[tid];
        p_arr[tid]   = __uint_as_float((unsigned int)(key >> 32) & 0x7FFFFFFFu);
        idx_arr[tid] = ~((unsigned int)(key & 0xFFFFFFFFull));
    }
    __syncthreads();

    if (tid == 0) {
        float cum = 0.0f, S = 0.0f;
        unsigned long long keep = 0ull;
        const float tp = top_ps[b];
        const int   tk = top_ks[b];
        for (int r = 0; r < 64; ++r) {
            float p = p_arr[r];
            cum = cum + p;
            float excl = cum - p;
            if (!(excl > tp) && (r < tk)) { keep |= (1ull << r); S = S + p; }
        }
        S_sh = S; keep_sh = keep;
    }
    __syncthreads();

    if (tid < 64) {
        unsigned long long pk = 0ull;
        if ((keep_sh >> tid) & 1ull) {
            float q  = p_arr[tid] / S_sh;
            float lp = logf(q);
            unsigned int idx = idx_arr[tid];
            float g = gumbel_at((unsigned int)b * (unsigned int)VV + idx);
            float vf = lp + g;
            pk = ((unsigned long long)enc_f32(vf) << 32)
               | (unsigned long long)(~idx);
        }
        for (int off = 1; off < 64; off <<= 1) {
            unsigned long long o = __shfl_xor(pk, off, 64);
            if (o > pk) pk = o;
        }
        if (tid == 0) {
            unsigned int token = ~((unsigned int)(pk & 0xFFFFFFFFull));
            dout[b] = (float)token;
        }
    }
}

extern "C" void kernel_launch(void* const* d_in, const int* in_sizes, int n_in,
                              void* d_out, int out_size, void* d_ws, size_t ws_size,
                              hipStream_t stream) {
    const float* emb   = (const float*)d_in[0];
    const float* hid   = (const float*)d_in[1];
    const int*   pos   = (const int*)d_in[2];
    const float* temps = (const float*)d_in[3];
    const float* tps   = (const float*)d_in[4];
    const int*   tks   = (const int*)d_in[5];
    float* out = (float*)d_out;

    if (ws_size >= WS_NEED) {
        float* ws = (float*)d_ws;
        gemv_part<<<dim3(VV / 32, KSPLIT), dim3(512), 0, stream>>>(emb, hid, pos, ws);
        reduce_ep<<<dim3(BB * VV / 512), dim3(512), 0, stream>>>(ws, temps, out);
    } else {
        gemv_fb<<<dim3(VV / 32), dim3(512), 0, stream>>>(emb, hid, pos, temps, out);
    }
    sample_kernel<<<dim3(BB), dim3(1024), 0, stream>>>(out, tps, tks);
}